// Round 1
// baseline (2580.208 us; speedup 1.0000x reference)
//
#include <hip/hip_runtime.h>
#include <math.h>

// Problem constants (from reference)
#define N_TOK 8192
#define DMODEL 1024
#define HID 2048
#define NEXP 8
#define TOPK 2
#define CAP 2560

// ---------------------------------------------------------------------------
// Gating: logits = x @ Wg + bg, softmax, top-2 (tie -> lowest index, matching
// jax.lax.top_k), per-block partial sums for importance / routing stats.
// One wave per token, 4 tokens per 256-thread block.
// ---------------------------------------------------------------------------
__global__ __launch_bounds__(256) void gate_kernel(
    const float* __restrict__ x, const float* __restrict__ Wg,
    const float* __restrict__ bg,
    int* __restrict__ flat_e, float* __restrict__ flat_p,
    float* __restrict__ imp_part, float* __restrict__ sel_part)
{
    __shared__ float s_imp[4][NEXP];
    __shared__ float s_sel[4][NEXP];
    const int wave = threadIdx.x >> 6;
    const int lane = threadIdx.x & 63;
    const int t = blockIdx.x * 4 + wave;

    float acc[NEXP];
#pragma unroll
    for (int e = 0; e < NEXP; ++e) acc[e] = 0.f;

    const float* xr = x + (size_t)t * DMODEL;
    for (int d = lane; d < DMODEL; d += 64) {
        const float xv = xr[d];
#pragma unroll
        for (int e = 0; e < NEXP; ++e) acc[e] += xv * Wg[d * NEXP + e];
    }
#pragma unroll
    for (int off = 32; off > 0; off >>= 1) {
#pragma unroll
        for (int e = 0; e < NEXP; ++e) acc[e] += __shfl_xor(acc[e], off);
    }
    // softmax (all lanes redundantly)
    float lg[NEXP], mx = -1e30f;
#pragma unroll
    for (int e = 0; e < NEXP; ++e) { lg[e] = acc[e] + bg[e]; mx = fmaxf(mx, lg[e]); }
    float p[NEXP], s = 0.f;
#pragma unroll
    for (int e = 0; e < NEXP; ++e) { p[e] = expf(lg[e] - mx); s += p[e]; }
    const float inv = 1.f / s;
#pragma unroll
    for (int e = 0; e < NEXP; ++e) p[e] *= inv;

    // top-2, stable (strict > keeps lowest index on ties)
    int i0 = 0;
#pragma unroll
    for (int e = 1; e < NEXP; ++e) if (p[e] > p[i0]) i0 = e;
    int i1 = (i0 == 0) ? 1 : 0;
#pragma unroll
    for (int e = 0; e < NEXP; ++e) if (e != i0 && p[e] > p[i1]) i1 = e;

    if (lane == 0) {
        flat_e[2 * t] = i0;  flat_e[2 * t + 1] = i1;
        flat_p[2 * t] = p[i0]; flat_p[2 * t + 1] = p[i1];
#pragma unroll
        for (int e = 0; e < NEXP; ++e) {
            s_imp[wave][e] = p[e];
            s_sel[wave][e] = (e == i0) ? p[i0] : ((e == i1) ? p[i1] : 0.f);
        }
    }
    __syncthreads();
    if (threadIdx.x < NEXP) {
        const int e = threadIdx.x;
        float a = 0.f, b = 0.f;
#pragma unroll
        for (int w = 0; w < 4; ++w) { a += s_imp[w][e]; b += s_sel[w][e]; }
        imp_part[blockIdx.x * NEXP + e] = a;
        sel_part[blockIdx.x * NEXP + e] = b;
    }
}

// ---------------------------------------------------------------------------
// Deterministic sequential rank scan over the N*K flat slot order.
// Single block, 1024 threads, 16 chunks. rank = #earlier slots w/ same expert.
// Also emits row_token (inverse map) and per-expert counts.
// ---------------------------------------------------------------------------
__global__ __launch_bounds__(1024) void scan_kernel(
    const int* __restrict__ flat_e, int* __restrict__ slot_rank,
    int* __restrict__ row_token, int* __restrict__ n_kept,
    int* __restrict__ cnt_full)
{
    __shared__ int wave_tot[16][NEXP];
    __shared__ int base[NEXP];
    const int tid = threadIdx.x, lane = tid & 63, w = tid >> 6;
    if (tid < NEXP) base[tid] = 0;
    __syncthreads();
    const unsigned long long ltmask =
        (lane == 0) ? 0ull : (~0ull >> (64 - lane));
    for (int chunk = 0; chunk < (N_TOK * TOPK) / 1024; ++chunk) {
        const int s = chunk * 1024 + tid;
        const int e = flat_e[s];
        int prefix = 0;
#pragma unroll
        for (int ee = 0; ee < NEXP; ++ee) {
            unsigned long long m = __ballot(e == ee);
            if (ee == e) prefix = __popcll(m & ltmask);
            if (lane == 0) wave_tot[w][ee] = __popcll(m);
        }
        __syncthreads();
        int before = base[e];
        for (int ww = 0; ww < w; ++ww) before += wave_tot[ww][e];
        const int rank = before + prefix;
        slot_rank[s] = rank;
        if (rank < CAP) row_token[e * CAP + rank] = s >> 1;
        __syncthreads();
        if (tid < NEXP) {
            int add = 0;
#pragma unroll
            for (int ww = 0; ww < 16; ++ww) add += wave_tot[ww][tid];
            base[tid] += add;
        }
        __syncthreads();
    }
    if (tid < NEXP) {
        n_kept[tid] = min(base[tid], CAP);
        cnt_full[tid] = base[tid];
    }
}

__device__ __forceinline__ float gelu_exact(float v) {
    return 0.5f * v * (1.f + erff(v * 0.70710678118654752440f));
}

// ---------------------------------------------------------------------------
// fp32 tiled GEMM per expert: out[e, m, n] = act(sum_k A[m,k] * W[e,k,n] + b[e,n])
// BM=BN=128, BK=16, 256 threads, 8x8 microtile.
// GATHER: A rows come from x via row_token (zero-pad past n_kept).
// ---------------------------------------------------------------------------
template <bool GATHER, bool GELU>
__global__ __launch_bounds__(256) void expert_gemm(
    const float* __restrict__ A, const float* __restrict__ W,
    const float* __restrict__ bias, float* __restrict__ out,
    const int* __restrict__ row_token, const int* __restrict__ n_kept,
    const int Kdim)
{
    constexpr int BM = 128, BN = 128, BK = 16;
    constexpr int NDIM = HID;
    __shared__ float As[BK][BM + 4];
    __shared__ float Bs[BK][BN];
    const int e = blockIdx.z;
    const int n_e = n_kept[e];
    const int m0 = blockIdx.y * BM;
    if (m0 >= n_e) return;           // whole tile beyond kept rows: skip
    const int n0 = blockIdx.x * BN;
    const float* We = W + (size_t)e * Kdim * NDIM;
    const float* be = bias + (size_t)e * NDIM;
    float* oute = out + ((size_t)e * CAP + m0) * NDIM;

    const int t = threadIdx.x;
    const int ar = t >> 2;           // 0..63  (A row within half-tile)
    const int ak = (t & 3) << 2;     // 0,4,8,12
    const float* arow[2];
#pragma unroll
    for (int p = 0; p < 2; ++p) {
        const int row = m0 + ar + p * 64;
        if (GATHER) {
            arow[p] = (row < n_e) ? (A + (size_t)row_token[e * CAP + row] * Kdim)
                                  : (const float*)nullptr;
        } else {
            arow[p] = A + ((size_t)e * CAP + row) * Kdim;  // h rows beyond n_e were
                                                           // written by gemm1 tiles
        }
    }
    const int brow = t >> 5;         // 0..7
    const int bcol = (t & 31) << 2;  // 0..124
    const int ty = t >> 4, tx = t & 15;

    float acc[8][8];
#pragma unroll
    for (int i = 0; i < 8; ++i)
#pragma unroll
        for (int j = 0; j < 8; ++j) acc[i][j] = 0.f;

    for (int k0 = 0; k0 < Kdim; k0 += BK) {
#pragma unroll
        for (int p = 0; p < 2; ++p) {
            float4 v = make_float4(0.f, 0.f, 0.f, 0.f);
            if (arow[p]) v = *(const float4*)(arow[p] + k0 + ak);
            As[ak + 0][ar + p * 64] = v.x;
            As[ak + 1][ar + p * 64] = v.y;
            As[ak + 2][ar + p * 64] = v.z;
            As[ak + 3][ar + p * 64] = v.w;
        }
#pragma unroll
        for (int p = 0; p < 2; ++p) {
            const float4 v =
                *(const float4*)(We + (size_t)(k0 + brow + p * 8) * NDIM + n0 + bcol);
            *(float4*)&Bs[brow + p * 8][bcol] = v;
        }
        __syncthreads();
#pragma unroll
        for (int kk = 0; kk < BK; ++kk) {
            float a[8], b[8];
            *(float4*)&a[0] = *(const float4*)&As[kk][ty * 8];
            *(float4*)&a[4] = *(const float4*)&As[kk][ty * 8 + 4];
            *(float4*)&b[0] = *(const float4*)&Bs[kk][tx * 8];
            *(float4*)&b[4] = *(const float4*)&Bs[kk][tx * 8 + 4];
#pragma unroll
            for (int i = 0; i < 8; ++i)
#pragma unroll
                for (int j = 0; j < 8; ++j)
                    acc[i][j] = fmaf(a[i], b[j], acc[i][j]);
        }
        __syncthreads();
    }
#pragma unroll
    for (int i = 0; i < 8; ++i) {
        float* orow = oute + (size_t)(ty * 8 + i) * NDIM + n0 + tx * 8;
        float v[8];
#pragma unroll
        for (int j = 0; j < 8; ++j) {
            v[j] = acc[i][j] + be[n0 + tx * 8 + j];
            if (GELU) v[j] = gelu_exact(v[j]);
        }
        *(float4*)&orow[0] = make_float4(v[0], v[1], v[2], v[3]);
        *(float4*)&orow[4] = make_float4(v[4], v[5], v[6], v[7]);
    }
}

// ---------------------------------------------------------------------------
// Combine: out[t,:] = w0 * y[e0,r0,:] + w1 * y[e1,r1,:]  (w=0 for dropped).
// One block per token; each token owns its row -> no atomics, deterministic.
// ---------------------------------------------------------------------------
__global__ __launch_bounds__(256) void combine_kernel(
    const float* __restrict__ y, const int* __restrict__ flat_e,
    const float* __restrict__ flat_p, const int* __restrict__ slot_rank,
    float* __restrict__ out)
{
    const int t = blockIdx.x;
    const int e0 = flat_e[2 * t], e1 = flat_e[2 * t + 1];
    const int r0 = slot_rank[2 * t], r1 = slot_rank[2 * t + 1];
    const bool k0 = r0 < CAP, k1 = r1 < CAP;
    const float w0 = k0 ? flat_p[2 * t] : 0.f;
    const float w1 = k1 ? flat_p[2 * t + 1] : 0.f;
    const float* y0 = y + ((size_t)e0 * CAP + (k0 ? r0 : 0)) * HID;
    const float* y1 = y + ((size_t)e1 * CAP + (k1 ? r1 : 0)) * HID;
    float* orow = out + (size_t)t * HID;
    for (int c = (threadIdx.x << 2); c < HID; c += 1024) {
        float4 a = k0 ? *(const float4*)(y0 + c) : make_float4(0.f, 0.f, 0.f, 0.f);
        float4 b = k1 ? *(const float4*)(y1 + c) : make_float4(0.f, 0.f, 0.f, 0.f);
        float4 r;
        r.x = w0 * a.x + w1 * b.x;
        r.y = w0 * a.y + w1 * b.y;
        r.z = w0 * a.z + w1 * b.z;
        r.w = w0 * a.w + w1 * b.w;
        *(float4*)(orow + c) = r;
    }
}

// ---------------------------------------------------------------------------
// Aux loss: var(importance)/E^2 + E * sum(usage * routing_weights).
// Fixed-order two-stage reduction -> deterministic.
// ---------------------------------------------------------------------------
__global__ __launch_bounds__(64) void aux_kernel(
    const float* __restrict__ imp_part, const float* __restrict__ sel_part,
    const int* __restrict__ cnt_full, float* __restrict__ out_aux,
    const int nparts)
{
    const int lane = threadIdx.x;
    __shared__ float imp_s[NEXP], sel_s[NEXP];
    for (int e = 0; e < NEXP; ++e) {
        float a = 0.f, b = 0.f;
        for (int i = lane; i < nparts; i += 64) {
            a += imp_part[i * NEXP + e];
            b += sel_part[i * NEXP + e];
        }
#pragma unroll
        for (int off = 32; off > 0; off >>= 1) {
            a += __shfl_xor(a, off);
            b += __shfl_xor(b, off);
        }
        if (lane == 0) { imp_s[e] = a; sel_s[e] = b; }
    }
    __syncthreads();
    if (lane == 0) {
        double mean = 0.0;
        for (int e = 0; e < NEXP; ++e) mean += imp_s[e];
        mean /= NEXP;
        double var = 0.0;
        for (int e = 0; e < NEXP; ++e) {
            const double d = (double)imp_s[e] - mean;
            var += d * d;
        }
        var /= NEXP;
        double load = 0.0;
        for (int e = 0; e < NEXP; ++e)
            load += ((double)cnt_full[e] / N_TOK) * ((double)sel_s[e] / N_TOK);
        load *= NEXP;
        out_aux[0] = (float)(var / (NEXP * NEXP) + load);
    }
}

// ---------------------------------------------------------------------------
extern "C" void kernel_launch(void* const* d_in, const int* in_sizes, int n_in,
                              void* d_out, int out_size, void* d_ws, size_t ws_size,
                              hipStream_t stream) {
    const float* x  = (const float*)d_in[0];
    const float* Wg = (const float*)d_in[1];
    const float* bg = (const float*)d_in[2];
    const float* W1 = (const float*)d_in[3];
    const float* b1 = (const float*)d_in[4];
    const float* W2 = (const float*)d_in[5];
    const float* b2 = (const float*)d_in[6];
    float* out = (float*)d_out;
    (void)in_sizes; (void)n_in; (void)out_size; (void)ws_size;

    char* ws = (char*)d_ws;
    size_t off = 0;
    auto alloc = [&](size_t bytes) -> void* {
        void* p = ws + off;
        off = (off + bytes + 255) & ~(size_t)255;
        return p;
    };
    int*   n_kept    = (int*)alloc(NEXP * sizeof(int));
    int*   cnt_full  = (int*)alloc(NEXP * sizeof(int));
    int*   flat_e    = (int*)alloc((size_t)N_TOK * TOPK * sizeof(int));
    float* flat_p    = (float*)alloc((size_t)N_TOK * TOPK * sizeof(float));
    int*   slot_rank = (int*)alloc((size_t)N_TOK * TOPK * sizeof(int));
    int*   row_tok   = (int*)alloc((size_t)NEXP * CAP * sizeof(int));
    float* imp_part  = (float*)alloc((size_t)(N_TOK / 4) * NEXP * sizeof(float));
    float* sel_part  = (float*)alloc((size_t)(N_TOK / 4) * NEXP * sizeof(float));
    float* hbuf      = (float*)alloc((size_t)NEXP * CAP * HID * sizeof(float));
    float* ybuf      = (float*)alloc((size_t)NEXP * CAP * HID * sizeof(float));
    // total ws use ~336 MB

    gate_kernel<<<N_TOK / 4, 256, 0, stream>>>(x, Wg, bg, flat_e, flat_p,
                                               imp_part, sel_part);
    scan_kernel<<<1, 1024, 0, stream>>>(flat_e, slot_rank, row_tok, n_kept, cnt_full);

    dim3 gg(HID / 128, CAP / 128, NEXP);
    expert_gemm<true,  true ><<<gg, 256, 0, stream>>>(x,    W1, b1, hbuf, row_tok, n_kept, DMODEL);
    expert_gemm<false, false><<<gg, 256, 0, stream>>>(hbuf, W2, b2, ybuf, row_tok, n_kept, HID);

    combine_kernel<<<N_TOK, 256, 0, stream>>>(ybuf, flat_e, flat_p, slot_rank, out);
    aux_kernel<<<1, 64, 0, stream>>>(imp_part, sel_part, cnt_full,
                                     out + (size_t)N_TOK * HID, N_TOK / 4);
}

// Round 2
// 611.407 us; speedup vs baseline: 4.2201x; 4.2201x over previous
//
#include <hip/hip_runtime.h>
#include <math.h>
#include <stdint.h>

#define N_TOK 8192
#define DMODEL 1024
#define HID 2048
#define NEXP 8
#define TOPK 2
#define CAP 2560

typedef __bf16 bf16x8 __attribute__((ext_vector_type(8)));
typedef float f32x4 __attribute__((ext_vector_type(4)));

__device__ __forceinline__ unsigned short f2b(float f) {
    unsigned int u = __builtin_bit_cast(unsigned int, f);
    u += 0x7fffu + ((u >> 16) & 1u);           // round-to-nearest-even
    return (unsigned short)(u >> 16);
}
__device__ __forceinline__ float b2f(unsigned short s) {
    unsigned int u = ((unsigned int)s) << 16;
    return __builtin_bit_cast(float, u);
}

// async global->LDS, 16B per lane. LDS dst must be wave-uniform (HW adds lane*16).
__device__ __forceinline__ void gload_lds16(const void* g, void* lds) {
    __builtin_amdgcn_global_load_lds(
        (const __attribute__((address_space(1))) unsigned int*)(uintptr_t)g,
        (__attribute__((address_space(3))) unsigned int*)(unsigned int)(uintptr_t)lds,
        16, 0, 0);
}

// ---------------------------------------------------------------------------
// Gating (exact f32 — routing must match reference bitwise-stably)
// ---------------------------------------------------------------------------
__global__ __launch_bounds__(256) void gate_kernel(
    const float* __restrict__ x, const float* __restrict__ Wg,
    const float* __restrict__ bg,
    int* __restrict__ flat_e, float* __restrict__ flat_p,
    float* __restrict__ imp_part, float* __restrict__ sel_part)
{
    __shared__ float s_imp[4][NEXP];
    __shared__ float s_sel[4][NEXP];
    const int wave = threadIdx.x >> 6;
    const int lane = threadIdx.x & 63;
    const int t = blockIdx.x * 4 + wave;

    float acc[NEXP];
#pragma unroll
    for (int e = 0; e < NEXP; ++e) acc[e] = 0.f;
    const float* xr = x + (size_t)t * DMODEL;
    for (int d = lane; d < DMODEL; d += 64) {
        const float xv = xr[d];
#pragma unroll
        for (int e = 0; e < NEXP; ++e) acc[e] += xv * Wg[d * NEXP + e];
    }
#pragma unroll
    for (int off = 32; off > 0; off >>= 1) {
#pragma unroll
        for (int e = 0; e < NEXP; ++e) acc[e] += __shfl_xor(acc[e], off);
    }
    float lg[NEXP], mx = -1e30f;
#pragma unroll
    for (int e = 0; e < NEXP; ++e) { lg[e] = acc[e] + bg[e]; mx = fmaxf(mx, lg[e]); }
    float p[NEXP], s = 0.f;
#pragma unroll
    for (int e = 0; e < NEXP; ++e) { p[e] = expf(lg[e] - mx); s += p[e]; }
    const float inv = 1.f / s;
#pragma unroll
    for (int e = 0; e < NEXP; ++e) p[e] *= inv;

    int i0 = 0;
#pragma unroll
    for (int e = 1; e < NEXP; ++e) if (p[e] > p[i0]) i0 = e;
    int i1 = (i0 == 0) ? 1 : 0;
#pragma unroll
    for (int e = 0; e < NEXP; ++e) if (e != i0 && p[e] > p[i1]) i1 = e;

    if (lane == 0) {
        flat_e[2 * t] = i0;  flat_e[2 * t + 1] = i1;
        flat_p[2 * t] = p[i0]; flat_p[2 * t + 1] = p[i1];
#pragma unroll
        for (int e = 0; e < NEXP; ++e) {
            s_imp[wave][e] = p[e];
            s_sel[wave][e] = (e == i0) ? p[i0] : ((e == i1) ? p[i1] : 0.f);
        }
    }
    __syncthreads();
    if (threadIdx.x < NEXP) {
        const int e = threadIdx.x;
        float a = 0.f, b = 0.f;
#pragma unroll
        for (int w = 0; w < 4; ++w) { a += s_imp[w][e]; b += s_sel[w][e]; }
        imp_part[blockIdx.x * NEXP + e] = a;
        sel_part[blockIdx.x * NEXP + e] = b;
    }
}

// ---------------------------------------------------------------------------
// Deterministic rank scan; fills row_token tail with N_TOK (zero pad row).
// ---------------------------------------------------------------------------
__global__ __launch_bounds__(1024) void scan_kernel(
    const int* __restrict__ flat_e, int* __restrict__ slot_rank,
    int* __restrict__ row_token, int* __restrict__ n_kept,
    int* __restrict__ cnt_full)
{
    __shared__ int wave_tot[16][NEXP];
    __shared__ int base[NEXP];
    const int tid = threadIdx.x, lane = tid & 63, w = tid >> 6;
    if (tid < NEXP) base[tid] = 0;
    __syncthreads();
    const unsigned long long ltmask =
        (lane == 0) ? 0ull : (~0ull >> (64 - lane));
    for (int chunk = 0; chunk < (N_TOK * TOPK) / 1024; ++chunk) {
        const int s = chunk * 1024 + tid;
        const int e = flat_e[s];
        int prefix = 0;
#pragma unroll
        for (int ee = 0; ee < NEXP; ++ee) {
            unsigned long long m = __ballot(e == ee);
            if (ee == e) prefix = __popcll(m & ltmask);
            if (lane == 0) wave_tot[w][ee] = __popcll(m);
        }
        __syncthreads();
        int before = base[e];
        for (int ww = 0; ww < w; ++ww) before += wave_tot[ww][e];
        const int rank = before + prefix;
        slot_rank[s] = rank;
        if (rank < CAP) row_token[e * CAP + rank] = s >> 1;
        __syncthreads();
        if (tid < NEXP) {
            int add = 0;
#pragma unroll
            for (int ww = 0; ww < 16; ++ww) add += wave_tot[ww][tid];
            base[tid] += add;
        }
        __syncthreads();
    }
    // tail fill: dropped/capacity-pad rows gather the zero row (index N_TOK)
    for (int i = tid; i < NEXP * CAP; i += 1024) {
        const int ee = i / CAP;
        const int r = i - ee * CAP;
        const int ne = base[ee] < CAP ? base[ee] : CAP;
        if (r >= ne) row_token[i] = N_TOK;
    }
    if (tid < NEXP) {
        n_kept[tid] = min(base[tid], CAP);
        cnt_full[tid] = base[tid];
    }
}

// ---------------------------------------------------------------------------
// x f32 [N][D] -> bf16 [N+1][D], row N = zeros (gather pad row)
// ---------------------------------------------------------------------------
__global__ __launch_bounds__(256) void convert_x(
    const float* __restrict__ x, unsigned short* __restrict__ xbf)
{
    const size_t i = ((size_t)blockIdx.x * 256 + threadIdx.x) * 4;
    float4 v = make_float4(0.f, 0.f, 0.f, 0.f);
    if (i < (size_t)N_TOK * DMODEL) v = *(const float4*)(x + i);
    ushort4 o;
    o.x = f2b(v.x); o.y = f2b(v.y); o.z = f2b(v.z); o.w = f2b(v.w);
    *(ushort4*)(xbf + i) = o;
}

// ---------------------------------------------------------------------------
// W [E][R][C] f32 -> Wt [E][C][R] bf16  (64x64 LDS tile transpose)
// ---------------------------------------------------------------------------
__global__ __launch_bounds__(256) void transpose_cvt(
    const float* __restrict__ W, unsigned short* __restrict__ Wt,
    const int R, const int Cdim)
{
    __shared__ unsigned short s[64][66];
    const int e = blockIdx.z;
    const int c0 = blockIdx.x * 64, r0 = blockIdx.y * 64;
    const float* We = W + (size_t)e * R * Cdim;
    unsigned short* Wte = Wt + (size_t)e * R * Cdim;
    const int lr = threadIdx.x >> 6;   // 0..3
    const int lc = threadIdx.x & 63;
#pragma unroll
    for (int i = 0; i < 16; ++i)
        s[lr + i * 4][lc] = f2b(We[(size_t)(r0 + lr + i * 4) * Cdim + c0 + lc]);
    __syncthreads();
#pragma unroll
    for (int i = 0; i < 16; ++i)
        Wte[(size_t)(c0 + lr + i * 4) * R + r0 + lc] = s[lc][lr + i * 4];
}

// ---------------------------------------------------------------------------
// bf16 MFMA GEMM (m97 structure): 128x128 tile, BK=64, 4 waves, 2-barrier loop.
// out[e,m,n] = act(sum_k A[m,k] * Wt[e,n,k] + bias[e,n]) -> bf16
// ---------------------------------------------------------------------------
template <bool GATHER, bool DO_GELU>
__global__ __launch_bounds__(256) void mfma_gemm(
    const unsigned short* __restrict__ A,   // GATHER: xbf[N+1][Kdim]; else [E][CAP][Kdim]
    const unsigned short* __restrict__ Wt,  // [E][HID][Kdim] (B^T)
    const float* __restrict__ bias,         // [E][HID]
    unsigned short* __restrict__ out,       // [E][CAP][HID]
    const int* __restrict__ row_token, const int* __restrict__ n_kept,
    const int Kdim)
{
    constexpr int BK = 64;
    __shared__ unsigned short As[128 * BK];
    __shared__ unsigned short Bs[128 * BK];

    const int e = blockIdx.z;
    const int n_e = n_kept[e];
    const int m0 = blockIdx.y * 128;
    if (m0 >= n_e) return;
    const int n0 = blockIdx.x * 128;

    const int tid = threadIdx.x;
    const int w = tid >> 6, lane = tid & 63;
    const int wr = w >> 1, wc = w & 1;
    const int l15 = lane & 15, lq = lane >> 4;

    // staging: wave w stages tile rows [w*32, w*32+32); 4 insts, 8 rows each.
    const int srow = lane >> 3;            // 0..7
    const int schunk = (lane & 7) * 8;     // elem offset (8 bf16 = 16B)
    const unsigned short* ag[4];
    const unsigned short* bg[4];
    unsigned short* adst[4];
    unsigned short* bdst[4];
#pragma unroll
    for (int j = 0; j < 4; ++j) {
        const int r = w * 32 + j * 8 + srow;
        size_t arow;
        if (GATHER) arow = (size_t)row_token[e * CAP + m0 + r] * Kdim;
        else        arow = ((size_t)e * CAP + m0 + r) * (size_t)Kdim;
        ag[j] = A + arow + schunk;
        bg[j] = Wt + ((size_t)e * HID + n0 + r) * (size_t)Kdim + schunk;
        adst[j] = As + (w * 32 + j * 8) * BK;
        bdst[j] = Bs + (w * 32 + j * 8) * BK;
    }

    f32x4 acc[4][4];
#pragma unroll
    for (int m = 0; m < 4; ++m)
#pragma unroll
        for (int n = 0; n < 4; ++n) acc[m][n] = (f32x4)0.f;

    for (int k0 = 0; k0 < Kdim; k0 += BK) {
#pragma unroll
        for (int j = 0; j < 4; ++j) {
            gload_lds16(ag[j] + k0, adst[j]);
            gload_lds16(bg[j] + k0, bdst[j]);
        }
        __syncthreads();   // compiler drains vmcnt before barrier
#pragma unroll
        for (int ks = 0; ks < 2; ++ks) {
            bf16x8 a[4], b[4];
#pragma unroll
            for (int m = 0; m < 4; ++m)
                a[m] = *(const bf16x8*)(As + (wr * 64 + m * 16 + l15) * BK + ks * 32 + lq * 8);
#pragma unroll
            for (int n = 0; n < 4; ++n)
                b[n] = *(const bf16x8*)(Bs + (wc * 64 + n * 16 + l15) * BK + ks * 32 + lq * 8);
#pragma unroll
            for (int m = 0; m < 4; ++m)
#pragma unroll
                for (int n = 0; n < 4; ++n)
                    acc[m][n] = __builtin_amdgcn_mfma_f32_16x16x32_bf16(
                        a[m], b[n], acc[m][n], 0, 0, 0);
        }
        __syncthreads();
    }

    // epilogue: C/D layout col=lane&15, row=(lane>>4)*4+j  [m89-verified]
    float bv[4];
#pragma unroll
    for (int n = 0; n < 4; ++n)
        bv[n] = bias[(size_t)e * HID + n0 + wc * 64 + n * 16 + l15];
#pragma unroll
    for (int m = 0; m < 4; ++m) {
#pragma unroll
        for (int j = 0; j < 4; ++j) {
            const int row = m0 + wr * 64 + m * 16 + lq * 4 + j;
            unsigned short* orow = out + ((size_t)e * CAP + row) * HID + n0 + wc * 64 + l15;
#pragma unroll
            for (int n = 0; n < 4; ++n) {
                float v = acc[m][n][j] + bv[n];
                if (DO_GELU) v = 0.5f * v * (1.f + erff(v * 0.70710678118654752440f));
                orow[n * 16] = f2b(v);
            }
        }
    }
}

// ---------------------------------------------------------------------------
// Combine: out[t,:] = w0*y[e0,r0,:] + w1*y[e1,r1,:]  (bf16 y, f32 out)
// ---------------------------------------------------------------------------
__global__ __launch_bounds__(256) void combine_kernel(
    const unsigned short* __restrict__ y, const int* __restrict__ flat_e,
    const float* __restrict__ flat_p, const int* __restrict__ slot_rank,
    float* __restrict__ out)
{
    const int t = blockIdx.x;
    const int e0 = flat_e[2 * t], e1 = flat_e[2 * t + 1];
    const int r0 = slot_rank[2 * t], r1 = slot_rank[2 * t + 1];
    const bool k0 = r0 < CAP, k1 = r1 < CAP;
    const float w0 = k0 ? flat_p[2 * t] : 0.f;
    const float w1 = k1 ? flat_p[2 * t + 1] : 0.f;
    const unsigned short* y0 = y + ((size_t)e0 * CAP + (k0 ? r0 : 0)) * HID;
    const unsigned short* y1 = y + ((size_t)e1 * CAP + (k1 ? r1 : 0)) * HID;
    float* orow = out + (size_t)t * HID;
    const int c = threadIdx.x * 8;           // 256 thr * 8 = 2048 = HID
    uint4 av = k0 ? *(const uint4*)(y0 + c) : make_uint4(0, 0, 0, 0);
    uint4 bv = k1 ? *(const uint4*)(y1 + c) : make_uint4(0, 0, 0, 0);
    float o[8];
    auto comb2 = [&](unsigned int a, unsigned int b, float* dst) {
        dst[0] = w0 * b2f((unsigned short)(a & 0xffffu)) +
                 w1 * b2f((unsigned short)(b & 0xffffu));
        dst[1] = w0 * b2f((unsigned short)(a >> 16)) +
                 w1 * b2f((unsigned short)(b >> 16));
    };
    comb2(av.x, bv.x, o + 0); comb2(av.y, bv.y, o + 2);
    comb2(av.z, bv.z, o + 4); comb2(av.w, bv.w, o + 6);
    *(float4*)(orow + c)     = make_float4(o[0], o[1], o[2], o[3]);
    *(float4*)(orow + c + 4) = make_float4(o[4], o[5], o[6], o[7]);
}

// ---------------------------------------------------------------------------
__global__ __launch_bounds__(64) void aux_kernel(
    const float* __restrict__ imp_part, const float* __restrict__ sel_part,
    const int* __restrict__ cnt_full, float* __restrict__ out_aux,
    const int nparts)
{
    const int lane = threadIdx.x;
    __shared__ float imp_s[NEXP], sel_s[NEXP];
    for (int e = 0; e < NEXP; ++e) {
        float a = 0.f, b = 0.f;
        for (int i = lane; i < nparts; i += 64) {
            a += imp_part[i * NEXP + e];
            b += sel_part[i * NEXP + e];
        }
#pragma unroll
        for (int off = 32; off > 0; off >>= 1) {
            a += __shfl_xor(a, off);
            b += __shfl_xor(b, off);
        }
        if (lane == 0) { imp_s[e] = a; sel_s[e] = b; }
    }
    __syncthreads();
    if (lane == 0) {
        double mean = 0.0;
        for (int e = 0; e < NEXP; ++e) mean += imp_s[e];
        mean /= NEXP;
        double var = 0.0;
        for (int e = 0; e < NEXP; ++e) {
            const double d = (double)imp_s[e] - mean;
            var += d * d;
        }
        var /= NEXP;
        double load = 0.0;
        for (int e = 0; e < NEXP; ++e)
            load += ((double)cnt_full[e] / N_TOK) * ((double)sel_s[e] / N_TOK);
        load *= NEXP;
        out_aux[0] = (float)(var / (NEXP * NEXP) + load);
    }
}

// ---------------------------------------------------------------------------
extern "C" void kernel_launch(void* const* d_in, const int* in_sizes, int n_in,
                              void* d_out, int out_size, void* d_ws, size_t ws_size,
                              hipStream_t stream) {
    const float* x  = (const float*)d_in[0];
    const float* Wg = (const float*)d_in[1];
    const float* bg = (const float*)d_in[2];
    const float* W1 = (const float*)d_in[3];
    const float* b1 = (const float*)d_in[4];
    const float* W2 = (const float*)d_in[5];
    const float* b2 = (const float*)d_in[6];
    float* out = (float*)d_out;
    (void)in_sizes; (void)n_in; (void)out_size; (void)ws_size;

    char* ws = (char*)d_ws;
    size_t off = 0;
    auto alloc = [&](size_t bytes) -> void* {
        void* p = ws + off;
        off = (off + bytes + 255) & ~(size_t)255;
        return p;
    };
    int*   n_kept    = (int*)alloc(NEXP * sizeof(int));
    int*   cnt_full  = (int*)alloc(NEXP * sizeof(int));
    int*   flat_e    = (int*)alloc((size_t)N_TOK * TOPK * sizeof(int));
    float* flat_p    = (float*)alloc((size_t)N_TOK * TOPK * sizeof(float));
    int*   slot_rank = (int*)alloc((size_t)N_TOK * TOPK * sizeof(int));
    int*   row_tok   = (int*)alloc((size_t)NEXP * CAP * sizeof(int));
    float* imp_part  = (float*)alloc((size_t)(N_TOK / 4) * NEXP * sizeof(float));
    float* sel_part  = (float*)alloc((size_t)(N_TOK / 4) * NEXP * sizeof(float));
    unsigned short* xbf  = (unsigned short*)alloc((size_t)(N_TOK + 1) * DMODEL * 2);
    unsigned short* w1t  = (unsigned short*)alloc((size_t)NEXP * DMODEL * HID * 2);
    unsigned short* w2t  = (unsigned short*)alloc((size_t)NEXP * HID * HID * 2);
    unsigned short* hbuf = (unsigned short*)alloc((size_t)NEXP * CAP * HID * 2);
    unsigned short* ybuf = (unsigned short*)alloc((size_t)NEXP * CAP * HID * 2);
    // total ws use ~287 MB

    convert_x<<<(N_TOK + 1) * DMODEL / 1024, 256, 0, stream>>>(x, xbf);
    transpose_cvt<<<dim3(HID / 64, DMODEL / 64, NEXP), 256, 0, stream>>>(W1, w1t, DMODEL, HID);
    transpose_cvt<<<dim3(HID / 64, HID / 64, NEXP), 256, 0, stream>>>(W2, w2t, HID, HID);

    gate_kernel<<<N_TOK / 4, 256, 0, stream>>>(x, Wg, bg, flat_e, flat_p,
                                               imp_part, sel_part);
    scan_kernel<<<1, 1024, 0, stream>>>(flat_e, slot_rank, row_tok, n_kept, cnt_full);

    dim3 gg(HID / 128, CAP / 128, NEXP);
    mfma_gemm<true,  true ><<<gg, 256, 0, stream>>>(xbf,  w1t, b1, hbuf, row_tok, n_kept, DMODEL);
    mfma_gemm<false, false><<<gg, 256, 0, stream>>>(hbuf, w2t, b2, ybuf, row_tok, n_kept, HID);

    combine_kernel<<<N_TOK, 256, 0, stream>>>(ybuf, flat_e, flat_p, slot_rank, out);
    aux_kernel<<<1, 64, 0, stream>>>(imp_part, sel_part, cnt_full,
                                     out + (size_t)N_TOK * HID, N_TOK / 4);
}

// Round 3
// 534.515 us; speedup vs baseline: 4.8272x; 1.1439x over previous
//
#include <hip/hip_runtime.h>
#include <math.h>
#include <stdint.h>

#define N_TOK 8192
#define DMODEL 1024
#define HID 2048
#define NEXP 8
#define TOPK 2
#define CAP 2560

typedef __bf16 bf16x8 __attribute__((ext_vector_type(8)));
typedef float f32x4 __attribute__((ext_vector_type(4)));

__device__ __forceinline__ unsigned short f2b(float f) {
    unsigned int u = __builtin_bit_cast(unsigned int, f);
    u += 0x7fffu + ((u >> 16) & 1u);           // round-to-nearest-even
    return (unsigned short)(u >> 16);
}
__device__ __forceinline__ float b2f(unsigned short s) {
    unsigned int u = ((unsigned int)s) << 16;
    return __builtin_bit_cast(float, u);
}

// async global->LDS, 16B per lane. LDS dst is wave-uniform base (+lane*16 in HW).
__device__ __forceinline__ void gload_lds16(const void* g, void* lds) {
    __builtin_amdgcn_global_load_lds(
        (const __attribute__((address_space(1))) unsigned int*)(uintptr_t)g,
        (__attribute__((address_space(3))) unsigned int*)(unsigned int)(uintptr_t)lds,
        16, 0, 0);
}

// ---------------------------------------------------------------------------
// Gating (exact f32)
// ---------------------------------------------------------------------------
__global__ __launch_bounds__(256) void gate_kernel(
    const float* __restrict__ x, const float* __restrict__ Wg,
    const float* __restrict__ bg,
    int* __restrict__ flat_e, float* __restrict__ flat_p,
    float* __restrict__ imp_part, float* __restrict__ sel_part)
{
    __shared__ float s_imp[4][NEXP];
    __shared__ float s_sel[4][NEXP];
    const int wave = threadIdx.x >> 6;
    const int lane = threadIdx.x & 63;
    const int t = blockIdx.x * 4 + wave;

    float acc[NEXP];
#pragma unroll
    for (int e = 0; e < NEXP; ++e) acc[e] = 0.f;
    const float* xr = x + (size_t)t * DMODEL;
    for (int d = lane; d < DMODEL; d += 64) {
        const float xv = xr[d];
#pragma unroll
        for (int e = 0; e < NEXP; ++e) acc[e] += xv * Wg[d * NEXP + e];
    }
#pragma unroll
    for (int off = 32; off > 0; off >>= 1) {
#pragma unroll
        for (int e = 0; e < NEXP; ++e) acc[e] += __shfl_xor(acc[e], off);
    }
    float lg[NEXP], mx = -1e30f;
#pragma unroll
    for (int e = 0; e < NEXP; ++e) { lg[e] = acc[e] + bg[e]; mx = fmaxf(mx, lg[e]); }
    float p[NEXP], s = 0.f;
#pragma unroll
    for (int e = 0; e < NEXP; ++e) { p[e] = expf(lg[e] - mx); s += p[e]; }
    const float inv = 1.f / s;
#pragma unroll
    for (int e = 0; e < NEXP; ++e) p[e] *= inv;

    int i0 = 0;
#pragma unroll
    for (int e = 1; e < NEXP; ++e) if (p[e] > p[i0]) i0 = e;
    int i1 = (i0 == 0) ? 1 : 0;
#pragma unroll
    for (int e = 0; e < NEXP; ++e) if (e != i0 && p[e] > p[i1]) i1 = e;

    if (lane == 0) {
        flat_e[2 * t] = i0;  flat_e[2 * t + 1] = i1;
        flat_p[2 * t] = p[i0]; flat_p[2 * t + 1] = p[i1];
#pragma unroll
        for (int e = 0; e < NEXP; ++e) {
            s_imp[wave][e] = p[e];
            s_sel[wave][e] = (e == i0) ? p[i0] : ((e == i1) ? p[i1] : 0.f);
        }
    }
    __syncthreads();
    if (threadIdx.x < NEXP) {
        const int e = threadIdx.x;
        float a = 0.f, b = 0.f;
#pragma unroll
        for (int w = 0; w < 4; ++w) { a += s_imp[w][e]; b += s_sel[w][e]; }
        imp_part[blockIdx.x * NEXP + e] = a;
        sel_part[blockIdx.x * NEXP + e] = b;
    }
}

// ---------------------------------------------------------------------------
// Deterministic rank scan; fills row_token tail with N_TOK (zero pad row).
// ---------------------------------------------------------------------------
__global__ __launch_bounds__(1024) void scan_kernel(
    const int* __restrict__ flat_e, int* __restrict__ slot_rank,
    int* __restrict__ row_token, int* __restrict__ n_kept,
    int* __restrict__ cnt_full)
{
    __shared__ int wave_tot[16][NEXP];
    __shared__ int base[NEXP];
    const int tid = threadIdx.x, lane = tid & 63, w = tid >> 6;
    if (tid < NEXP) base[tid] = 0;
    __syncthreads();
    const unsigned long long ltmask =
        (lane == 0) ? 0ull : (~0ull >> (64 - lane));
    for (int chunk = 0; chunk < (N_TOK * TOPK) / 1024; ++chunk) {
        const int s = chunk * 1024 + tid;
        const int e = flat_e[s];
        int prefix = 0;
#pragma unroll
        for (int ee = 0; ee < NEXP; ++ee) {
            unsigned long long m = __ballot(e == ee);
            if (ee == e) prefix = __popcll(m & ltmask);
            if (lane == 0) wave_tot[w][ee] = __popcll(m);
        }
        __syncthreads();
        int before = base[e];
        for (int ww = 0; ww < w; ++ww) before += wave_tot[ww][e];
        const int rank = before + prefix;
        slot_rank[s] = rank;
        if (rank < CAP) row_token[e * CAP + rank] = s >> 1;
        __syncthreads();
        if (tid < NEXP) {
            int add = 0;
#pragma unroll
            for (int ww = 0; ww < 16; ++ww) add += wave_tot[ww][tid];
            base[tid] += add;
        }
        __syncthreads();
    }
    for (int i = tid; i < NEXP * CAP; i += 1024) {
        const int ee = i / CAP;
        const int r = i - ee * CAP;
        const int ne = base[ee] < CAP ? base[ee] : CAP;
        if (r >= ne) row_token[i] = N_TOK;
    }
    if (tid < NEXP) {
        n_kept[tid] = min(base[tid], CAP);
        cnt_full[tid] = base[tid];
    }
}

// ---------------------------------------------------------------------------
// x f32 [N][D] -> bf16 [N+1][D], row N = zeros (gather pad row)
// ---------------------------------------------------------------------------
__global__ __launch_bounds__(256) void convert_x(
    const float* __restrict__ x, unsigned short* __restrict__ xbf)
{
    const size_t i = ((size_t)blockIdx.x * 256 + threadIdx.x) * 4;
    float4 v = make_float4(0.f, 0.f, 0.f, 0.f);
    if (i < (size_t)N_TOK * DMODEL) v = *(const float4*)(x + i);
    ushort4 o;
    o.x = f2b(v.x); o.y = f2b(v.y); o.z = f2b(v.z); o.w = f2b(v.w);
    *(ushort4*)(xbf + i) = o;
}

// ---------------------------------------------------------------------------
// W [E][R][C] f32 -> Wt [E][C][R] bf16  (64x64 LDS tile transpose)
// ---------------------------------------------------------------------------
__global__ __launch_bounds__(256) void transpose_cvt(
    const float* __restrict__ W, unsigned short* __restrict__ Wt,
    const int R, const int Cdim)
{
    __shared__ unsigned short s[64][66];
    const int e = blockIdx.z;
    const int c0 = blockIdx.x * 64, r0 = blockIdx.y * 64;
    const float* We = W + (size_t)e * R * Cdim;
    unsigned short* Wte = Wt + (size_t)e * R * Cdim;
    const int lr = threadIdx.x >> 6;
    const int lc = threadIdx.x & 63;
#pragma unroll
    for (int i = 0; i < 16; ++i)
        s[lr + i * 4][lc] = f2b(We[(size_t)(r0 + lr + i * 4) * Cdim + c0 + lc]);
    __syncthreads();
#pragma unroll
    for (int i = 0; i < 16; ++i)
        Wte[(size_t)(c0 + lr + i * 4) * R + r0 + lc] = s[lc][lr + i * 4];
}

// ---------------------------------------------------------------------------
// 256x256 bf16 MFMA GEMM, BK=64, 8 waves, phase-split K-loop, counted vmcnt,
// st_16x32 LDS swizzle (linear gload_lds dst + inverse-swizzled global src).
// out[e,m,n] = act(sum_k A[m,k] * Wt[e,n,k] + bias[e,n]) -> bf16
// ---------------------------------------------------------------------------
#define VMGATE() do { asm volatile("s_waitcnt vmcnt(4)" ::: "memory"); \
                      __builtin_amdgcn_sched_barrier(0); } while (0)
#define NOGATE() ((void)0)

#define PHASE(mf0, STAGE_STMT, TAIL_STMT) do {                                   \
    bf16x8 a0 = lda(c, (mf0), 0), a1 = lda(c, (mf0), 1);                         \
    bf16x8 a2 = lda(c, (mf0) + 1, 0), a3 = lda(c, (mf0) + 1, 1);                 \
    STAGE_STMT;                                                                  \
    __builtin_amdgcn_s_barrier();                                                \
    asm volatile("s_waitcnt lgkmcnt(0)" ::: "memory");                           \
    __builtin_amdgcn_sched_barrier(0);                                           \
    __builtin_amdgcn_s_setprio(1);                                               \
    _Pragma("unroll")                                                            \
    for (int nf = 0; nf < 4; ++nf) {                                             \
        acc[(mf0)][nf] = __builtin_amdgcn_mfma_f32_16x16x32_bf16(                \
            a0, bfr[nf][0], acc[(mf0)][nf], 0, 0, 0);                            \
        acc[(mf0)][nf] = __builtin_amdgcn_mfma_f32_16x16x32_bf16(                \
            a1, bfr[nf][1], acc[(mf0)][nf], 0, 0, 0);                            \
        acc[(mf0) + 1][nf] = __builtin_amdgcn_mfma_f32_16x16x32_bf16(            \
            a2, bfr[nf][0], acc[(mf0) + 1][nf], 0, 0, 0);                        \
        acc[(mf0) + 1][nf] = __builtin_amdgcn_mfma_f32_16x16x32_bf16(            \
            a3, bfr[nf][1], acc[(mf0) + 1][nf], 0, 0, 0);                        \
    }                                                                            \
    __builtin_amdgcn_s_setprio(0);                                               \
    TAIL_STMT;                                                                   \
    __builtin_amdgcn_s_barrier();                                                \
} while (0)

template <bool GATHER, bool DO_GELU>
__global__ __launch_bounds__(512, 2) void mfma_gemm256(
    const unsigned short* __restrict__ A,   // GATHER: xbf[N+1][K]; else [E][CAP][K]
    const unsigned short* __restrict__ Wt,  // [E][HID][K] (B^T)
    const float* __restrict__ bias,         // [E][HID]
    unsigned short* __restrict__ out,       // [E][CAP][HID]
    const int* __restrict__ row_token, const int* __restrict__ n_kept,
    const int Kdim)
{
    __shared__ unsigned short smem[65536];  // 128 KB: A[2][32KB] | B[2][32KB]

    // XCD-chunked swizzle (grid = 640 = 8*80, 80 blocks per expert)
    int bid = blockIdx.x;
    const int cpx = gridDim.x >> 3;
    bid = (bid & 7) * cpx + (bid >> 3);
    const int e = bid / 80;
    const int rem = bid - e * 80;
    const int m0 = (rem >> 3) * 256;
    const int n0 = (rem & 7) * 256;

    const int n_e = n_kept[e];
    if (m0 >= n_e) return;

    const int t = threadIdx.x;
    const int w = t >> 6, lane = t & 63;
    const int wm = w >> 2, wn = w & 3;        // 2 x 4 wave grid
    const int l15 = lane & 15, lq = lane >> 4;

    // ---- staging source bases (element offsets), per (half h, call cc) ----
    long abase[2][2], bbase[2][2];
#pragma unroll
    for (int h = 0; h < 2; ++h) {
#pragma unroll
        for (int cc = 0; cc < 2; ++cc) {
            const int srow = h * 128 + cc * 64 + (t >> 3);
            const int skoff = ((t & 7) * 8) ^ ((srow & 4) << 2);  // inv-swz src
            long ar;
            if (GATHER) ar = (long)row_token[e * CAP + m0 + srow] * Kdim;
            else        ar = ((long)e * CAP + m0 + srow) * (long)Kdim;
            abase[h][cc] = ar + skoff;
            bbase[h][cc] = ((long)e * HID + n0 + srow) * (long)Kdim + skoff;
        }
    }

    auto stageA = [&](int buf, int h0, int ktile) {
        const long ko = (long)ktile * 64;
        char* base = (char*)smem + buf * 32768 + h0 * 16384 + w * 1024;
        gload_lds16(A + (h0 ? abase[1][0] : abase[0][0]) + ko, base);
        gload_lds16(A + (h0 ? abase[1][1] : abase[0][1]) + ko, base + 8192);
    };
    auto stageB = [&](int buf, int h0, int ktile) {
        const long ko = (long)ktile * 64;
        char* base = (char*)smem + 65536 + buf * 32768 + h0 * 16384 + w * 1024;
        gload_lds16(Wt + (h0 ? bbase[1][0] : bbase[0][0]) + ko, base);
        gload_lds16(Wt + (h0 ? bbase[1][1] : bbase[0][1]) + ko, base + 8192);
    };

    // ---- swizzled fragment reads (row&4 -> flip byte bit5) ----
    const int sx = (l15 & 4) << 3;
    const int kbx0 = (lq * 16) ^ sx;
    const int kbx1 = (64 + lq * 16) ^ sx;
    auto lda = [&](int cbuf, int mf, int ks) -> bf16x8 {
        return *(const bf16x8*)((const char*)smem + cbuf * 32768 +
                                (wm * 128 + mf * 16 + l15) * 128 + (ks ? kbx1 : kbx0));
    };
    auto ldb = [&](int cbuf, int nf, int ks) -> bf16x8 {
        return *(const bf16x8*)((const char*)smem + 65536 + cbuf * 32768 +
                                (wn * 64 + nf * 16 + l15) * 128 + (ks ? kbx1 : kbx0));
    };

    f32x4 acc[8][4];
#pragma unroll
    for (int m = 0; m < 8; ++m)
#pragma unroll
        for (int n = 0; n < 4; ++n) acc[m][n] = (f32x4)0.f;

    const int NT = Kdim >> 6;

    // ---- prologue: A(t0)->buf0, B(t0)->buf0, B(t1)->buf1 ----
    stageA(0, 0, 0); stageA(0, 1, 0);
    stageB(0, 0, 0); stageB(0, 1, 0);
    stageB(1, 0, 1); stageB(1, 1, 1);
    VMGATE();                      // allow B(t1) (4 loads) in flight
    __builtin_amdgcn_s_barrier();

    // ---- main loop: per K-tile, 4 phases, 8 barriers, one vmcnt(4) ----
    for (int kt = 0; kt < NT; ++kt) {
        const int c = kt & 1, o = c ^ 1;
        const int ktA = min(kt + 1, NT - 1);   // A for tile kt+1 -> buf o
        const int ktB = min(kt + 2, NT - 1);   // B for tile kt+2 -> buf c

        bf16x8 bfr[4][2];
#pragma unroll
        for (int nf = 0; nf < 4; ++nf) {
            bfr[nf][0] = ldb(c, nf, 0);
            bfr[nf][1] = ldb(c, nf, 1);
        }
        PHASE(0, stageA(o, 0, ktA), NOGATE());
        PHASE(2, stageA(o, 1, ktA), NOGATE());
        PHASE(4, stageB(c, 0, ktB), NOGATE());
        PHASE(6, stageB(c, 1, ktB), VMGATE());
    }

    // ---- epilogue: bias + optional GELU, bf16 store ----
    const float* be = bias + (size_t)e * HID;
    float bv[4];
#pragma unroll
    for (int nf = 0; nf < 4; ++nf)
        bv[nf] = be[n0 + wn * 64 + nf * 16 + l15];
#pragma unroll
    for (int mf = 0; mf < 8; ++mf) {
#pragma unroll
        for (int j = 0; j < 4; ++j) {
            const int row = m0 + wm * 128 + mf * 16 + lq * 4 + j;
            unsigned short* orow =
                out + ((size_t)e * CAP + row) * HID + n0 + wn * 64 + l15;
#pragma unroll
            for (int nf = 0; nf < 4; ++nf) {
                float v = acc[mf][nf][j] + bv[nf];
                if (DO_GELU) v = 0.5f * v * (1.f + erff(v * 0.70710678118654752440f));
                orow[nf * 16] = f2b(v);
            }
        }
    }
}

// ---------------------------------------------------------------------------
// Combine: out[t,:] = w0*y[e0,r0,:] + w1*y[e1,r1,:]  (bf16 y, f32 out)
// ---------------------------------------------------------------------------
__global__ __launch_bounds__(256) void combine_kernel(
    const unsigned short* __restrict__ y, const int* __restrict__ flat_e,
    const float* __restrict__ flat_p, const int* __restrict__ slot_rank,
    float* __restrict__ out)
{
    const int t = blockIdx.x;
    const int e0 = flat_e[2 * t], e1 = flat_e[2 * t + 1];
    const int r0 = slot_rank[2 * t], r1 = slot_rank[2 * t + 1];
    const bool k0 = r0 < CAP, k1 = r1 < CAP;
    const float w0 = k0 ? flat_p[2 * t] : 0.f;
    const float w1 = k1 ? flat_p[2 * t + 1] : 0.f;
    const unsigned short* y0 = y + ((size_t)e0 * CAP + (k0 ? r0 : 0)) * HID;
    const unsigned short* y1 = y + ((size_t)e1 * CAP + (k1 ? r1 : 0)) * HID;
    float* orow = out + (size_t)t * HID;
    const int c = threadIdx.x * 8;
    uint4 av = k0 ? *(const uint4*)(y0 + c) : make_uint4(0, 0, 0, 0);
    uint4 bv = k1 ? *(const uint4*)(y1 + c) : make_uint4(0, 0, 0, 0);
    float o[8];
    auto comb2 = [&](unsigned int a, unsigned int b, float* dst) {
        dst[0] = w0 * b2f((unsigned short)(a & 0xffffu)) +
                 w1 * b2f((unsigned short)(b & 0xffffu));
        dst[1] = w0 * b2f((unsigned short)(a >> 16)) +
                 w1 * b2f((unsigned short)(b >> 16));
    };
    comb2(av.x, bv.x, o + 0); comb2(av.y, bv.y, o + 2);
    comb2(av.z, bv.z, o + 4); comb2(av.w, bv.w, o + 6);
    *(float4*)(orow + c)     = make_float4(o[0], o[1], o[2], o[3]);
    *(float4*)(orow + c + 4) = make_float4(o[4], o[5], o[6], o[7]);
}

// ---------------------------------------------------------------------------
__global__ __launch_bounds__(64) void aux_kernel(
    const float* __restrict__ imp_part, const float* __restrict__ sel_part,
    const int* __restrict__ cnt_full, float* __restrict__ out_aux,
    const int nparts)
{
    const int lane = threadIdx.x;
    __shared__ float imp_s[NEXP], sel_s[NEXP];
    for (int e = 0; e < NEXP; ++e) {
        float a = 0.f, b = 0.f;
        for (int i = lane; i < nparts; i += 64) {
            a += imp_part[i * NEXP + e];
            b += sel_part[i * NEXP + e];
        }
#pragma unroll
        for (int off = 32; off > 0; off >>= 1) {
            a += __shfl_xor(a, off);
            b += __shfl_xor(b, off);
        }
        if (lane == 0) { imp_s[e] = a; sel_s[e] = b; }
    }
    __syncthreads();
    if (lane == 0) {
        double mean = 0.0;
        for (int e = 0; e < NEXP; ++e) mean += imp_s[e];
        mean /= NEXP;
        double var = 0.0;
        for (int e = 0; e < NEXP; ++e) {
            const double d = (double)imp_s[e] - mean;
            var += d * d;
        }
        var /= NEXP;
        double load = 0.0;
        for (int e = 0; e < NEXP; ++e)
            load += ((double)cnt_full[e] / N_TOK) * ((double)sel_s[e] / N_TOK);
        load *= NEXP;
        out_aux[0] = (float)(var / (NEXP * NEXP) + load);
    }
}

// ---------------------------------------------------------------------------
extern "C" void kernel_launch(void* const* d_in, const int* in_sizes, int n_in,
                              void* d_out, int out_size, void* d_ws, size_t ws_size,
                              hipStream_t stream) {
    const float* x  = (const float*)d_in[0];
    const float* Wg = (const float*)d_in[1];
    const float* bg = (const float*)d_in[2];
    const float* W1 = (const float*)d_in[3];
    const float* b1 = (const float*)d_in[4];
    const float* W2 = (const float*)d_in[5];
    const float* b2 = (const float*)d_in[6];
    float* out = (float*)d_out;
    (void)in_sizes; (void)n_in; (void)out_size; (void)ws_size;

    char* ws = (char*)d_ws;
    size_t off = 0;
    auto alloc = [&](size_t bytes) -> void* {
        void* p = ws + off;
        off = (off + bytes + 255) & ~(size_t)255;
        return p;
    };
    int*   n_kept    = (int*)alloc(NEXP * sizeof(int));
    int*   cnt_full  = (int*)alloc(NEXP * sizeof(int));
    int*   flat_e    = (int*)alloc((size_t)N_TOK * TOPK * sizeof(int));
    float* flat_p    = (float*)alloc((size_t)N_TOK * TOPK * sizeof(float));
    int*   slot_rank = (int*)alloc((size_t)N_TOK * TOPK * sizeof(int));
    int*   row_tok   = (int*)alloc((size_t)NEXP * CAP * sizeof(int));
    float* imp_part  = (float*)alloc((size_t)(N_TOK / 4) * NEXP * sizeof(float));
    float* sel_part  = (float*)alloc((size_t)(N_TOK / 4) * NEXP * sizeof(float));
    unsigned short* xbf  = (unsigned short*)alloc((size_t)(N_TOK + 1) * DMODEL * 2);
    unsigned short* w1t  = (unsigned short*)alloc((size_t)NEXP * DMODEL * HID * 2);
    unsigned short* w2t  = (unsigned short*)alloc((size_t)NEXP * HID * HID * 2);
    unsigned short* hbuf = (unsigned short*)alloc((size_t)NEXP * CAP * HID * 2);
    unsigned short* ybuf = (unsigned short*)alloc((size_t)NEXP * CAP * HID * 2);

    convert_x<<<(N_TOK + 1) * DMODEL / 1024, 256, 0, stream>>>(x, xbf);
    transpose_cvt<<<dim3(HID / 64, DMODEL / 64, NEXP), 256, 0, stream>>>(W1, w1t, DMODEL, HID);
    transpose_cvt<<<dim3(HID / 64, HID / 64, NEXP), 256, 0, stream>>>(W2, w2t, HID, HID);

    gate_kernel<<<N_TOK / 4, 256, 0, stream>>>(x, Wg, bg, flat_e, flat_p,
                                               imp_part, sel_part);
    scan_kernel<<<1, 1024, 0, stream>>>(flat_e, slot_rank, row_tok, n_kept, cnt_full);

    const int nblk = NEXP * (CAP / 256) * (HID / 256);   // 640
    mfma_gemm256<true,  true ><<<nblk, 512, 0, stream>>>(xbf,  w1t, b1, hbuf, row_tok, n_kept, DMODEL);
    mfma_gemm256<false, false><<<nblk, 512, 0, stream>>>(hbuf, w2t, b2, ybuf, row_tok, n_kept, HID);

    combine_kernel<<<N_TOK, 256, 0, stream>>>(ybuf, flat_e, flat_p, slot_rank, out);
    aux_kernel<<<1, 64, 0, stream>>>(imp_part, sel_part, cnt_full,
                                     out + (size_t)N_TOK * HID, N_TOK / 4);
}